// Round 2
// baseline (561.301 us; speedup 1.0000x reference)
//
#include <hip/hip_runtime.h>
#include <cstdint>
#include <cstddef>

typedef unsigned short u16;
typedef __attribute__((ext_vector_type(8))) short short8;
typedef __attribute__((ext_vector_type(4))) float f32x4;

#define DIM 512
#define C2  256
#define HD  32
#define SCALE_Q 0.17677669529663689f

__device__ __forceinline__ float bf2f(u16 u){ return __uint_as_float(((unsigned)u) << 16); }
__device__ __forceinline__ u16 f2bf(float f){
  unsigned u = __float_as_uint(f);
  unsigned r = (u + 0x7FFFu + ((u >> 16) & 1u)) >> 16;
  return (u16)r;
}

__device__ __forceinline__ f32x4 mfma16(short8 a, short8 b, f32x4 c){
  return __builtin_amdgcn_mfma_f32_16x16x32_bf16(a, b, c, 0, 0, 0);
}

// ---------------- weight transpose + fp32->bf16: WT[n][k] = bf16(W[k][n]) ----------------
__global__ void transpose_kernel(const float* __restrict__ W, u16* __restrict__ WT, int K, int N){
  int idx = blockIdx.x * 256 + threadIdx.x;
  if (idx >= K * N) return;
  int n = idx / K;
  int k = idx - n * K;
  WT[idx] = f2bf(W[(size_t)k * N + n]);
}

// ---------------- LayerNorm over last dim (512), one wave per row; fp32 in -> bf16 out ----------------
__global__ __launch_bounds__(256) void ln_kernel(const float* __restrict__ x, const float* __restrict__ g,
                                                 const float* __restrict__ bta, u16* __restrict__ out){
  int row  = blockIdx.x * 4 + (threadIdx.x >> 6);
  int lane = threadIdx.x & 63;
  size_t base = (size_t)row * DIM + lane * 8;
  float4 v0 = *(const float4*)(x + base);
  float4 v1 = *(const float4*)(x + base + 4);
  float f[8] = {v0.x, v0.y, v0.z, v0.w, v1.x, v1.y, v1.z, v1.w};
  float s = 0.f;
#pragma unroll
  for (int j = 0; j < 8; j++) s += f[j];
#pragma unroll
  for (int m = 1; m < 64; m <<= 1) s += __shfl_xor(s, m, 64);
  float mean = s * (1.0f / DIM);
  float vs = 0.f;
#pragma unroll
  for (int j = 0; j < 8; j++){ float d = f[j] - mean; vs += d * d; }
#pragma unroll
  for (int m = 1; m < 64; m <<= 1) vs += __shfl_xor(vs, m, 64);
  float rstd = rsqrtf(vs * (1.0f / DIM) + 1e-5f);
  float4 g0 = *(const float4*)(g + lane * 8);
  float4 g1 = *(const float4*)(g + lane * 8 + 4);
  float4 b0 = *(const float4*)(bta + lane * 8);
  float4 b1 = *(const float4*)(bta + lane * 8 + 4);
  float gg[8] = {g0.x, g0.y, g0.z, g0.w, g1.x, g1.y, g1.z, g1.w};
  float bb[8] = {b0.x, b0.y, b0.z, b0.w, b1.x, b1.y, b1.z, b1.w};
  short8 o;
#pragma unroll
  for (int j = 0; j < 8; j++){
    float r = (f[j] - mean) * rstd * gg[j] + bb[j];
    o[j] = (short)f2bf(r);
  }
  *(short8*)(out + base) = o;
}

// ---------------- GEMM: C[M x N] = A[M x K] @ W[K x N] (+bias, +epilogue) ----------------
// A bf16 row-major (lda); WT = bf16 W-transposed [N x K] row-major. Tile 128x128, 4 waves.
// EPI: 0 = bias; 1 = bias + fp32 residual R; 2 = bias + exact gelu
template<int EPI, bool OUT_BF16>
__global__ __launch_bounds__(256) void gemm_kernel(
    const u16* __restrict__ A, int lda,
    const u16* __restrict__ WT,
    const float* __restrict__ bias,
    const float* R, int ldr,
    void* Cv, int ldc, int K)
{
  constexpr int SA = 40;  // padded LDS row stride (elems)
  __shared__ u16 Asm[128 * SA];
  __shared__ u16 Bsm[128 * SA];
  int row0 = blockIdx.x * 128, col0 = blockIdx.y * 128;
  int tid  = threadIdx.x;
  int lane = tid & 63, wave = tid >> 6;
  int wr = wave >> 1, wc = wave & 1;
  int l16 = lane & 15, lhi = lane >> 4;
  f32x4 acc[4][4] = {};

  for (int k0 = 0; k0 < K; k0 += 32){
#pragma unroll
    for (int i = 0; i < 2; i++){
      int r  = (tid >> 2) + i * 64;
      int kc = (tid & 3) * 8;
      *(short8*)&Asm[r * SA + kc] = *(const short8*)&A[(size_t)(row0 + r) * lda + k0 + kc];
      *(short8*)&Bsm[r * SA + kc] = *(const short8*)&WT[(size_t)(col0 + r) * K + k0 + kc];
    }
    __syncthreads();
    short8 af[4], bfr[4];
#pragma unroll
    for (int m = 0; m < 4; m++) af[m]  = *(const short8*)&Asm[(wr * 64 + m * 16 + l16) * SA + lhi * 8];
#pragma unroll
    for (int n = 0; n < 4; n++) bfr[n] = *(const short8*)&Bsm[(wc * 64 + n * 16 + l16) * SA + lhi * 8];
#pragma unroll
    for (int m = 0; m < 4; m++)
#pragma unroll
      for (int n = 0; n < 4; n++)
        acc[m][n] = mfma16(af[m], bfr[n], acc[m][n]);
    __syncthreads();
  }

#pragma unroll
  for (int m = 0; m < 4; m++){
#pragma unroll
    for (int n = 0; n < 4; n++){
      int c = col0 + wc * 64 + n * 16 + l16;
      float bb = bias[c];
#pragma unroll
      for (int i = 0; i < 4; i++){
        int r = row0 + wr * 64 + m * 16 + lhi * 4 + i;
        float v = acc[m][n][i] + bb;
        if constexpr (EPI == 1) v += R[(size_t)r * ldr + c];
        if constexpr (EPI == 2) v = 0.5f * v * (1.0f + erff(v * 0.70710678118654752f));
        if constexpr (OUT_BF16) ((u16*)Cv)[(size_t)r * ldc + c] = f2bf(v);
        else                    ((float*)Cv)[(size_t)r * ldc + c] = v;
      }
    }
  }
}

// ---------------- windowed attention + LePE, one wave per (window, head) ----------------
__global__ __launch_bounds__(64) void attn_kernel(
    const u16* __restrict__ qkv, const float* __restrict__ lw,
    const float* __restrict__ lb, u16* __restrict__ out)
{
  __shared__ float Ks[64][36];
  __shared__ float Vs[64][36];
  __shared__ float Wle[32][9];
  __shared__ float Lb[32];
  int head = blockIdx.x & 7, win = blockIdx.x >> 3;
  int wx = win & 7, wy = (win >> 3) & 7, b = win >> 6;
  int l  = threadIdx.x;           // query pixel in window
  int py = l >> 3, px = l & 7;
  size_t t = (size_t)b * 4096 + (size_t)(wy * 8 + py) * 64 + (wx * 8 + px);
  const u16* base = qkv + t * 768 + head * HD;

  float q[32];
#pragma unroll
  for (int j = 0; j < 32; j += 8){
    short8 vq = *(const short8*)(base + j);
    short8 vk = *(const short8*)(base + 256 + j);
    short8 vv = *(const short8*)(base + 512 + j);
#pragma unroll
    for (int e = 0; e < 8; e++){
      q[j + e]     = bf2f((u16)vq[e]) * SCALE_Q;
      Ks[l][j + e] = bf2f((u16)vk[e]);
      Vs[l][j + e] = bf2f((u16)vv[e]);
    }
  }
  for (int i = l; i < 288; i += 64) Wle[i / 9][i % 9] = lw[(head * 32 + i / 9) * 9 + (i % 9)];
  if (l < 32) Lb[l] = lb[head * 32 + l];
  __syncthreads();

  float sc[64];
  float mx = -1e30f;
#pragma unroll
  for (int k = 0; k < 64; k++){
    float s = 0.f;
#pragma unroll
    for (int d = 0; d < 32; d++) s += q[d] * Ks[k][d];
    sc[k] = s; mx = fmaxf(mx, s);
  }
  float sum = 0.f;
#pragma unroll
  for (int k = 0; k < 64; k++){ float e = __expf(sc[k] - mx); sc[k] = e; sum += e; }
  float inv = 1.0f / sum;
  float o[32];
#pragma unroll
  for (int d = 0; d < 32; d++) o[d] = 0.f;
#pragma unroll
  for (int k = 0; k < 64; k++){
    float p = sc[k] * inv;
#pragma unroll
    for (int d = 0; d < 32; d++) o[d] += p * Vs[k][d];
  }
  // LePE: depthwise 3x3 over the 8x8 window (zero pad at window edges)
#pragma unroll
  for (int ky = 0; ky < 3; ky++){
    int yy = py + ky - 1;
    if (yy < 0 || yy >= 8) continue;
#pragma unroll
    for (int kx = 0; kx < 3; kx++){
      int xx = px + kx - 1;
      if (xx < 0 || xx >= 8) continue;
      int kp = yy * 8 + xx;
#pragma unroll
      for (int d = 0; d < 32; d++) o[d] += Wle[d][ky * 3 + kx] * Vs[kp][d];
    }
  }
  u16* op = out + t * DIM + head * HD;
#pragma unroll
  for (int d = 0; d < 32; d++) op[d] = f2bf(o[d] + Lb[d]);
}

// ---------------- full-image depthwise 3x3 on img[..., 256:], thread = channel ----------------
__global__ __launch_bounds__(256) void convloc_kernel(const u16* __restrict__ img,
    const float* __restrict__ w, u16* __restrict__ out){
  int c  = threadIdx.x;
  int pg = blockIdx.x;            // 2048 groups of 16 pixels
  int b  = pg >> 8;
  int p0 = (pg & 255) * 16;
  float wt[9];
#pragma unroll
  for (int i = 0; i < 9; i++) wt[i] = w[c * 9 + i];
  for (int pi = 0; pi < 16; pi++){
    int p = p0 + pi;
    int y = p >> 6, x = p & 63;
    float acc = 0.f;
#pragma unroll
    for (int ky = 0; ky < 3; ky++){
      int yy = y + ky - 1;
      if (yy < 0 || yy >= 64) continue;
#pragma unroll
      for (int kx = 0; kx < 3; kx++){
        int xx = x + kx - 1;
        if (xx < 0 || xx >= 64) continue;
        acc += wt[ky * 3 + kx] * bf2f(img[((size_t)b * 4096 + yy * 64 + xx) * DIM + C2 + c]);
      }
    }
    out[((size_t)b * 4096 + p) * DIM + C2 + c] = f2bf(acc);
  }
}

extern "C" void kernel_launch(void* const* d_in, const int* in_sizes, int n_in,
                              void* d_out, int out_size, void* d_ws, size_t ws_size,
                              hipStream_t stream){
  const float* x      = (const float*)d_in[0];
  const float* n1g    = (const float*)d_in[1];
  const float* n1b    = (const float*)d_in[2];
  const float* qkv_w  = (const float*)d_in[3];
  const float* qkv_b  = (const float*)d_in[4];
  const float* lepe_w = (const float*)d_in[5];
  const float* lepe_b = (const float*)d_in[6];
  const float* conv_w = (const float*)d_in[7];
  const float* proj_w = (const float*)d_in[8];
  const float* proj_b = (const float*)d_in[9];
  const float* n2g    = (const float*)d_in[10];
  const float* n2b    = (const float*)d_in[11];
  const float* fc1_w  = (const float*)d_in[12];
  const float* fc1_b  = (const float*)d_in[13];
  const float* fc2_w  = (const float*)d_in[14];
  const float* fc2_b  = (const float*)d_in[15];
  float* out = (float*)d_out;

  char* ws = (char*)d_ws;
  // ws layout (bytes):
  //   img   bf16 [0,        33554432)
  //   qkvb  bf16 [33554432, 83886080)
  //   localb bf16[83886080, 117440512)
  //   y     bf16 [0, 33554432)          (reuses img; img dead after convloc)
  //   h     bf16 [33554432, 167772160)  (reuses qkvb+localb; dead after proj)
  //   weights    [167772160, ~172.9M)
  // xa (fp32, 64MB) lives in d_out; fully rewritten by proj before any read,
  // fc2 does an element-bijective in-place out = xa + fc2(h).
  u16* img     = (u16*)(ws + 0);
  u16* qkvb    = (u16*)(ws + 33554432ull);
  u16* localb  = (u16*)(ws + 83886080ull);
  u16* y       = (u16*)(ws + 0);
  u16* h       = (u16*)(ws + 33554432ull);
  u16* qkv_wT  = (u16*)(ws + 167772160ull);
  u16* proj_wT = (u16*)(ws + 167772160ull + 393216ull);
  u16* fc1_wT  = (u16*)(ws + 167772160ull + 393216ull + 524288ull);
  u16* fc2_wT  = (u16*)(ws + 167772160ull + 393216ull + 524288ull + 2097152ull);
  float* xa    = (float*)d_out;

  transpose_kernel<<<768, 256, 0, stream>>>(qkv_w, qkv_wT, 256, 768);
  transpose_kernel<<<1024, 256, 0, stream>>>(proj_w, proj_wT, 512, 512);
  transpose_kernel<<<4096, 256, 0, stream>>>(fc1_w, fc1_wT, 512, 2048);
  transpose_kernel<<<4096, 256, 0, stream>>>(fc2_w, fc2_wT, 2048, 512);

  ln_kernel<<<8192, 256, 0, stream>>>(x, n1g, n1b, img);

  dim3 gq(256, 6);
  gemm_kernel<0, true><<<gq, 256, 0, stream>>>(img, DIM, qkv_wT, qkv_b, nullptr, 0, qkvb, 768, 256);

  attn_kernel<<<4096, 64, 0, stream>>>(qkvb, lepe_w, lepe_b, localb);
  convloc_kernel<<<2048, 256, 0, stream>>>(img, conv_w, localb);

  dim3 gp(256, 4);
  gemm_kernel<1, false><<<gp, 256, 0, stream>>>(localb, DIM, proj_wT, proj_b, x, DIM, xa, DIM, 512);

  ln_kernel<<<8192, 256, 0, stream>>>(xa, n2g, n2b, y);

  dim3 g1(256, 16);
  gemm_kernel<2, true><<<g1, 256, 0, stream>>>(y, DIM, fc1_wT, fc1_b, nullptr, 0, h, 2048, 512);

  dim3 g2(256, 4);
  gemm_kernel<1, false><<<g2, 256, 0, stream>>>(h, 2048, fc2_wT, fc2_b, xa, DIM, out, DIM, 2048);
}